// Round 1
// baseline (116.398 us; speedup 1.0000x reference)
//
#include <hip/hip_runtime.h>
#include <math.h>

#define B_N 4096
#define H_N 256
#define I_N 32
#define G3  768

// workspace layout (bytes)
#define WS_IDX     0            // 4096 ints
#define WS_COUNTS  16384        // 32 ints
#define WS_CURSOR  16512        // 32 ints
#define WS_OFFS    16640        // 33 ints
#define WS_NITEMS  16776        // 1 int
#define WS_ITEMS   16784        // up to 320 ints
#define WS_SORTED  32768        // 4096 ints
#define WS_W2      65536        // 6291456 floats (24 MB)
#define WS_NEEDED  (65536 + (size_t)6291456 * 4)

__device__ __forceinline__ float sigm(float x) { return 1.0f / (1.0f + expf(-x)); }

// --- phase B1: one-hot -> expert index, histogram -------------------------
__global__ void k_idx_count(const float* __restrict__ inp, int* __restrict__ idx_arr,
                            int* __restrict__ counts) {
    int b = blockIdx.x * blockDim.x + threadIdx.x;
    if (b >= B_N) return;
    const float4* p = (const float4*)(inp + b * I_N);
    int idx = 0;
#pragma unroll
    for (int k = 0; k < 8; ++k) {
        float4 v = p[k];
        if (v.x > 0.5f) idx = k * 4 + 0;
        if (v.y > 0.5f) idx = k * 4 + 1;
        if (v.z > 0.5f) idx = k * 4 + 2;
        if (v.w > 0.5f) idx = k * 4 + 3;
    }
    idx_arr[b] = idx;
    atomicAdd(counts + idx, 1);
}

// --- phase B2: prefix offsets + work-item plan (tiny, serial) -------------
__global__ void k_plan(const int* __restrict__ counts, int* __restrict__ offs,
                       int* __restrict__ cursor, int* __restrict__ nitems,
                       int* __restrict__ items) {
    if (threadIdx.x != 0) return;
    int off = 0, nit = 0;
    for (int i = 0; i < I_N; ++i) {
        offs[i] = off;
        int c = counts[i];
        off += c;
        int nch = (c + 15) >> 4;               // BM = 16
        for (int ch = 0; ch < nch; ++ch) items[nit++] = (i << 16) | ch;
        cursor[i] = 0;
    }
    offs[I_N] = off;
    *nitems = nit;
}

// --- phase B3: scatter batch ids into expert-sorted order -----------------
__global__ void k_scatter(const int* __restrict__ idx_arr, const int* __restrict__ offs,
                          int* __restrict__ cursor, int* __restrict__ sorted) {
    int b = blockIdx.x * blockDim.x + threadIdx.x;
    if (b >= B_N) return;
    int i = idx_arr[b];
    int pos = atomicAdd(cursor + i, 1);
    sorted[offs[i] + pos] = b;
}

// --- phase R: repack W[g][h][i] -> W2[i][h][g] (coalesced both sides) -----
__global__ void k_repack(const float* __restrict__ w, float* __restrict__ w2) {
    __shared__ float tile[64][33];
    int gc = blockIdx.x;          // 0..11 (g chunk of 64)
    int h  = blockIdx.y;          // 0..255
    int g0 = gc * 64;
    int t = threadIdx.x;
#pragma unroll
    for (int k = 0; k < 8; ++k) {
        int e = t + k * 256;
        int i = e & 31, dg = e >> 5;
        tile[dg][i] = w[((g0 + dg) * H_N + h) * I_N + i];
    }
    __syncthreads();
#pragma unroll
    for (int k = 0; k < 8; ++k) {
        int f = t + k * 256;
        int dg = f & 63, ii = f >> 6;
        w2[(ii * H_N + h) * G3 + g0 + dg] = tile[dg][ii];
    }
}

// --- phase C: grouped matvec-GEMM + fused GRU gate epilogue ---------------
__global__ __launch_bounds__(256) void k_gemm(
    const float* __restrict__ w2, const float* __restrict__ hx,
    const float* __restrict__ b_ih, const float* __restrict__ b_hh,
    const int* __restrict__ sorted, const int* __restrict__ offs,
    const int* __restrict__ counts, const int* __restrict__ nitems,
    const int* __restrict__ items, float* __restrict__ out) {
    int bid = blockIdx.x;
    if (bid >= *nitems) return;
    int item = items[bid];
    int ex = item >> 16, ch = item & 0xffff;
    int base = offs[ex] + ch * 16;
    int cnt = counts[ex];
    int M = min(16, cnt - ch * 16);
    int t = threadIdx.x;

    __shared__ float hxs[16][H_N];
    __shared__ int bids[16];
    if (t < 16) bids[t] = (t < M) ? sorted[base + t] : -1;
    __syncthreads();
#pragma unroll
    for (int m = 0; m < 16; ++m) {
        int b = bids[m];
        hxs[m][t] = (b >= 0) ? hx[b * H_N + t] : 0.0f;
    }
    __syncthreads();

    float acc0[16], acc1[16], acc2[16];
#pragma unroll
    for (int m = 0; m < 16; ++m) { acc0[m] = 0.f; acc1[m] = 0.f; acc2[m] = 0.f; }

    const float* wp = w2 + ex * (H_N * G3) + t;
    for (int h = 0; h < H_N; h += 4) {
        float w0[4], w1[4], w2r[4];
#pragma unroll
        for (int k = 0; k < 4; ++k) {
            w0[k] = wp[0]; w1[k] = wp[256]; w2r[k] = wp[512];
            wp += G3;
        }
#pragma unroll
        for (int m = 0; m < 16; ++m) {
            float4 x = *(const float4*)(&hxs[m][h]);
            acc0[m] = fmaf(w0[0], x.x, acc0[m]);
            acc1[m] = fmaf(w1[0], x.x, acc1[m]);
            acc2[m] = fmaf(w2r[0], x.x, acc2[m]);
            acc0[m] = fmaf(w0[1], x.y, acc0[m]);
            acc1[m] = fmaf(w1[1], x.y, acc1[m]);
            acc2[m] = fmaf(w2r[1], x.y, acc2[m]);
            acc0[m] = fmaf(w0[2], x.z, acc0[m]);
            acc1[m] = fmaf(w1[2], x.z, acc1[m]);
            acc2[m] = fmaf(w2r[2], x.z, acc2[m]);
            acc0[m] = fmaf(w0[3], x.w, acc0[m]);
            acc1[m] = fmaf(w1[3], x.w, acc1[m]);
            acc2[m] = fmaf(w2r[3], x.w, acc2[m]);
        }
    }

    float bi0 = b_ih[t * I_N + ex], bi1 = b_ih[(256 + t) * I_N + ex], bi2 = b_ih[(512 + t) * I_N + ex];
    float bh0 = b_hh[t * I_N + ex], bh1 = b_hh[(256 + t) * I_N + ex], bh2 = b_hh[(512 + t) * I_N + ex];
    for (int m = 0; m < M; ++m) {
        int b = bids[m];
        float xv = hxs[m][t];
        float r = sigm(bi0 + acc0[m] + bh0);
        float u = sigm(bi1 + acc1[m] + bh1);
        float n = tanhf(bi2 + r * (acc2[m] + bh2));
        out[b * H_N + t] = u * xv + (1.0f - u) * n;
    }
}

// --- fallback: correct but slow (gathered weight reads), if ws too small --
__global__ void k_naive(const float* __restrict__ inp, const float* __restrict__ hx,
                        const float* __restrict__ w, const float* __restrict__ b_ih,
                        const float* __restrict__ b_hh, float* __restrict__ out) {
    int b = blockIdx.x;
    int t = threadIdx.x;
    __shared__ float sx[H_N];
    __shared__ int sidx;
    if (t == 0) {
        int idx = 0;
        for (int i = 0; i < I_N; ++i)
            if (inp[b * I_N + i] > 0.5f) idx = i;
        sidx = idx;
    }
    sx[t] = hx[b * H_N + t];
    __syncthreads();
    int i = sidx;
    float a0 = 0.f, a1 = 0.f, a2 = 0.f;
    for (int h = 0; h < H_N; ++h) {
        float xv = sx[h];
        a0 = fmaf(w[(t * H_N + h) * I_N + i], xv, a0);
        a1 = fmaf(w[((256 + t) * H_N + h) * I_N + i], xv, a1);
        a2 = fmaf(w[((512 + t) * H_N + h) * I_N + i], xv, a2);
    }
    float r = sigm(b_ih[t * I_N + i] + a0 + b_hh[t * I_N + i]);
    float u = sigm(b_ih[(256 + t) * I_N + i] + a1 + b_hh[(256 + t) * I_N + i]);
    float n = tanhf(b_ih[(512 + t) * I_N + i] + r * (a2 + b_hh[(512 + t) * I_N + i]));
    out[b * H_N + t] = u * sx[t] + (1.0f - u) * n;
}

extern "C" void kernel_launch(void* const* d_in, const int* in_sizes, int n_in,
                              void* d_out, int out_size, void* d_ws, size_t ws_size,
                              hipStream_t stream) {
    const float* inp  = (const float*)d_in[0];
    const float* hx   = (const float*)d_in[1];
    const float* w    = (const float*)d_in[2];
    const float* b_ih = (const float*)d_in[3];
    const float* b_hh = (const float*)d_in[4];
    float* out = (float*)d_out;

    if (ws_size < WS_NEEDED) {
        k_naive<<<B_N, H_N, 0, stream>>>(inp, hx, w, b_ih, b_hh, out);
        return;
    }

    char* ws = (char*)d_ws;
    int* idx_arr = (int*)(ws + WS_IDX);
    int* counts  = (int*)(ws + WS_COUNTS);
    int* cursor  = (int*)(ws + WS_CURSOR);
    int* offs    = (int*)(ws + WS_OFFS);
    int* nitems  = (int*)(ws + WS_NITEMS);
    int* items   = (int*)(ws + WS_ITEMS);
    int* sorted  = (int*)(ws + WS_SORTED);
    float* w2    = (float*)(ws + WS_W2);

    hipMemsetAsync(counts, 0, 128, stream);                 // counts (cursor zeroed in k_plan)
    k_idx_count<<<B_N / 256, 256, 0, stream>>>(inp, idx_arr, counts);
    k_plan<<<1, 64, 0, stream>>>(counts, offs, cursor, nitems, items);
    k_scatter<<<B_N / 256, 256, 0, stream>>>(idx_arr, offs, cursor, sorted);
    k_repack<<<dim3(12, 256), 256, 0, stream>>>(w, w2);
    k_gemm<<<288, 256, 0, stream>>>(w2, hx, b_ih, b_hh, sorted, offs, counts, nitems, items, out);
}